// Round 2
// baseline (305.493 us; speedup 1.0000x reference)
//
#include <hip/hip_runtime.h>
#include <stdint.h>

// DPS_55336358642719  (round-8: fused single-kernel, grid barrier,
//                      prefetch x under topk's VALU phase)
// in[0]: x_high  (8,3,1024,1024) f32
// in[1]: scores  (8,16,16)       f32
// out:   patches (128,3,128,128) f32
//
// ws layout: counts[8][16][256] u32 (131072 B) + barrier u32 (at +131072)
//
// NOTE: measured harness floor is ~145 us of fillBufferAligned re-poison
// (402 MB @ ~82% HBM peak) per timed iteration — not addressable from here.
//
// Round-8: topk (VALU-bound, ~5 us, HBM idle) + patches (HBM-bound, ~18 us)
// + 3 launch gaps fused into ONE 512-block kernel:
//   phase 1: grid-stride the 4000 (b,sample) topk units; each unit also
//            issues 8 KB of strided x prefetch (32 MB total) kept live via
//            asm — x fetch overlaps topk compute + warms L3.
//   grid barrier (device-scope atomics; 512 blocks == 2/CU co-resident,
//            guaranteed by __launch_bounds__(256,2))
//   phase 2: grid-stride the 768 patch units (16 ptiles x 3 c x 16 b*kg).

#define NSAMP 500
#define DDIM  256
#define GRID  512

// ---------------- threefry2x32 (JAX-exact, key = seed 42) ----------------
__device__ __forceinline__ void threefry2x32_0_42(uint32_t x0, uint32_t x1,
                                                  uint32_t& o0, uint32_t& o1) {
  const uint32_t k0 = 0u, k1 = 42u;
  const uint32_t k2 = k0 ^ k1 ^ 0x1BD11BDAu;
  x0 += k0; x1 += k1;
#define TF_ROUND(r) { x0 += x1; x1 = (x1 << (r)) | (x1 >> (32 - (r))); x1 ^= x0; }
  TF_ROUND(13) TF_ROUND(15) TF_ROUND(26) TF_ROUND(6)
  x0 += k1; x1 += k2 + 1u;
  TF_ROUND(17) TF_ROUND(29) TF_ROUND(16) TF_ROUND(24)
  x0 += k2; x1 += k0 + 2u;
  TF_ROUND(13) TF_ROUND(15) TF_ROUND(26) TF_ROUND(6)
  x0 += k0; x1 += k1 + 3u;
  TF_ROUND(17) TF_ROUND(29) TF_ROUND(16) TF_ROUND(24)
  x0 += k1; x1 += k2 + 4u;
  TF_ROUND(13) TF_ROUND(15) TF_ROUND(26) TF_ROUND(6)
  x0 += k2; x1 += k0 + 5u;
#undef TF_ROUND
  o0 = x0; o1 = x1;
}

// XLA's ErfInv32 (Giles polynomial), fp-contract off for fidelity
__device__ __forceinline__ float xla_erfinv(float x) {
#pragma clang fp contract(off)
  float w = -log1pf(-x * x);
  float p;
  if (w < 5.0f) {
    w = w - 2.5f;
    p = 2.81022636e-08f;
    p = 3.43273939e-07f + p * w;
    p = -3.5233877e-06f + p * w;
    p = -4.39150654e-06f + p * w;
    p = 0.00021858087f + p * w;
    p = -0.00125372503f + p * w;
    p = -0.00417768164f + p * w;
    p = 0.246640727f + p * w;
    p = 1.50140941f + p * w;
  } else {
    w = sqrtf(w) - 3.0f;
    p = -0.000200214257f;
    p = 0.000100950558f + p * w;
    p = 0.00134934322f + p * w;
    p = -0.00367342844f + p * w;
    p = 0.00573950773f + p * w;
    p = -0.0076224613f + p * w;
    p = 0.00943887047f + p * w;
    p = 1.00167406f + p * w;
    p = 2.83297682f + p * w;
  }
  return p * x;
}

__global__ void __launch_bounds__(256, 2)
fused_kernel(const float* __restrict__ x, const float* __restrict__ scores,
             uint32_t* __restrict__ counts, uint32_t* __restrict__ bar,
             float* __restrict__ out) {
  const int lb  = blockIdx.x;     // 0..511
  const int tid = threadIdx.x;
  const int lane = tid & 63, wv = tid >> 6;

  // ---- topk-phase shared ----
  __shared__ float s_wmx[4], s_wmn[4], s_wtl[4];
  __shared__ int   s_wcc[4], s_wtot[4];
  __shared__ __align__(16) float s_candPv[DDIM];
  __shared__ int   s_candIdx[DDIM];
  __shared__ unsigned char s_selMark[DDIM];
  // ---- patches-phase shared ----
  __shared__ __align__(16) float s_cw[DDIM * 8];
  __shared__ int s_colOff[DDIM];
  __shared__ int s_wcnt[4];

  // =========================== PHASE 1: topk ===========================
  {
#pragma clang fp contract(off)
    const int d = tid;
    for (int gs = lb; gs < 8 * NSAMP; gs += GRID) {
      // prefetch: 512 float4 per unit, strided uniformly over x (32.5% of
      // the 6.29M-float4 buffer across 4000 units). Kept live via asm below.
      const float4* pfp = (const float4*)x + (size_t)gs * 1572;
      const float4 pf0 = pfp[(tid << 1) + 0];
      const float4 pf1 = pfp[(tid << 1) + 1];

      const int b = gs / NSAMP;
      const int n = gs - b * NSAMP;

      const float sc = scores[b * DDIM + d];

      // block min/max of scores (exact op order preserved)
      float mx = sc, mn = sc;
      for (int off = 32; off > 0; off >>= 1) {
        mx = fmaxf(mx, __shfl_xor(mx, off));
        mn = fminf(mn, __shfl_xor(mn, off));
      }
      if (lane == 0) { s_wmx[wv] = mx; s_wmn[wv] = mn; }
      s_selMark[d] = 0;
      __syncthreads();
      mx = fmaxf(fmaxf(s_wmx[0], s_wmx[1]), fmaxf(s_wmx[2], s_wmx[3]));
      mn = fminf(fminf(s_wmn[0], s_wmn[1]), fminf(s_wmn[2], s_wmn[3]));
      const float denom = (mx - mn) + 1e-5f;

      // perturbed value (bit-identical expression order)
      const uint32_t j = (uint32_t)(b * (NSAMP * DDIM) + n * DDIM + d);
      uint32_t o0, o1;
      threefry2x32_0_42(0u, j, o0, o1);
      const uint32_t bits = o0 ^ o1;
      const float flo = -0.99999994f;  // nextafter(-1,0) in f32
      float f = __uint_as_float((bits >> 9) | 0x3f800000u) - 1.0f;
      float u = f * 2.0f + flo;
      u = fmaxf(flo, u);
      const float z = 1.41421356237f * xla_erfinv(u);
      const float sv = (sc - mn) / denom;
      const float pv = sv + z * 0.05f;

      // screen: T_lb = min over 16 groups-of-16 of group max
      float gmx = pv;
      gmx = fmaxf(gmx, __shfl_xor(gmx, 1));
      gmx = fmaxf(gmx, __shfl_xor(gmx, 2));
      gmx = fmaxf(gmx, __shfl_xor(gmx, 4));
      gmx = fmaxf(gmx, __shfl_xor(gmx, 8));
      float tl = gmx;
      tl = fminf(tl, __shfl_xor(tl, 16));
      tl = fminf(tl, __shfl_xor(tl, 32));
      if (lane == 0) s_wtl[wv] = tl;
      __syncthreads();
      const float T_lb = fminf(fminf(s_wtl[0], s_wtl[1]), fminf(s_wtl[2], s_wtl[3]));

      // compact candidates ascending by d (preserves index order)
      const bool candf = (pv >= T_lb);
      const unsigned long long cm = __ballot(candf);
      if (lane == 0) s_wcc[wv] = __popcll(cm);
      __syncthreads();
      int cbase = 0;
      for (int w2 = 0; w2 < wv; ++w2) cbase += s_wcc[w2];
      const int C = s_wcc[0] + s_wcc[1] + s_wcc[2] + s_wcc[3];  // >= 16
      if (candf) {
        const int pos = cbase + __popcll(cm & ((1ull << lane) - 1ull));
        s_candPv[pos] = pv;
        s_candIdx[pos] = d;
      }
      const int Cr = (C + 3) & ~3;
      if (d >= C && d < Cr) s_candPv[d] = -1e30f;
      __syncthreads();

      // exact rank among candidates (superset proof: any value > or == a
      // candidate is itself >= T_lb; compaction preserves index order)
      if (d < C) {
        const float cpv = s_candPv[d];
        int gc = 0, eqb = 0;
        const float4* c4 = (const float4*)s_candPv;
        for (int e4 = 0; e4 < (Cr >> 2); ++e4) {
          const float4 o = c4[e4];
          const int e = e4 << 2;
          gc += (o.x > cpv); gc += (o.y > cpv); gc += (o.z > cpv); gc += (o.w > cpv);
          eqb += (o.x == cpv) & ((e + 0) < d);
          eqb += (o.y == cpv) & ((e + 1) < d);
          eqb += (o.z == cpv) & ((e + 2) < d);
          eqb += (o.w == cpv) & ((e + 3) < d);
        }
        if ((gc + eqb) < 16) s_selMark[s_candIdx[d]] = 1;
      }
      __syncthreads();

      // rank among selected, ascending index (the jnp.sort step)
      const bool sel = s_selMark[d] != 0;
      const unsigned long long m = __ballot(sel);
      if (lane == 0) s_wtot[wv] = __popcll(m);
      __syncthreads();
      int r = __popcll(m & ((1ull << lane) - 1ull));
      for (int w2 = 0; w2 < wv; ++w2) r += s_wtot[w2];

      if (sel) atomicAdd(&counts[(b << 12) + (r << 8) + d], 1u);

      // keep prefetch live (forces the loads; waitcnt lands here, after
      // the whole compute body — latency fully hidden)
      asm volatile("" :: "v"(pf0.x), "v"(pf0.y), "v"(pf0.z), "v"(pf0.w),
                         "v"(pf1.x), "v"(pf1.y), "v"(pf1.z), "v"(pf1.w));
      __syncthreads();  // shared-mem reuse guard for next unit
    }
  }

  // ======================== grid barrier ========================
  __threadfence();   // release: counts atomics visible device-wide
  __syncthreads();
  if (tid == 0) {
    __hip_atomic_fetch_add(bar, 1u, __ATOMIC_ACQ_REL, __HIP_MEMORY_SCOPE_AGENT);
    while (__hip_atomic_load(bar, __ATOMIC_ACQUIRE, __HIP_MEMORY_SCOPE_AGENT)
           < gridDim.x) {
      __builtin_amdgcn_s_sleep(2);
    }
  }
  __syncthreads();
  __threadfence();   // acquire: invalidate stale L1/L2 before counts reads

  // =========================== PHASE 2: patches ===========================
  for (int uu = lb; uu < 768; uu += GRID) {
    __syncthreads();                  // shared-mem reuse guard
    const int p0 = (uu & 15) << 3;    // 8 rows per unit
    const int c  = (uu >> 4) % 3;
    const int zb = uu / 48;           // b*2 + kg
    const int b  = zb >> 1;
    const int k0 = (zb & 1) << 3;     // 0 or 8

    // load weights (coalesced per k), compact active columns ascending
    {
      float wreg[8];
      bool any = false;
#pragma unroll
      for (int kk = 0; kk < 8; ++kk) {
        float w = (float)counts[((b * 16 + k0 + kk) << 8) + tid] / 500.0f;
        wreg[kk] = w;
        any = any || (w != 0.0f);
      }
      unsigned long long m = __ballot(any);
      if (lane == 0) s_wcnt[wv] = __popcll(m);
      __syncthreads();
      int base = 0;
      for (int w2 = 0; w2 < wv; ++w2) base += s_wcnt[w2];
      if (any) {
        int pos = base + __popcll(m & ((1ull << lane) - 1ull));
        s_colOff[pos] = ((tid >> 4) << 16) | ((tid & 15) << 6);  // i*65536+w*64
#pragma unroll
        for (int kk = 0; kk < 8; ++kk) s_cw[pos * 8 + kk] = wreg[kk];
      }
      __syncthreads();
    }
    const int nact = s_wcnt[0] + s_wcnt[1] + s_wcnt[2] + s_wcnt[3];

    const int q0   = (tid & 31) << 2;   // 0,4,...,124
    const int slot = tid >> 5;          // 0..7
    const int ps   = p0 + slot;

    // bounds masks: bit w of qm / bit i of ym says the float4 is in-bounds
    int qm = 0xFFFF, ym = 0xFFFF;
    if (q0 < 32) qm &= ~1;
    if (q0 > 92) qm &= ~0x8000;
    if (ps < 32) ym &= ~1;
    if (ps > 95) ym &= ~0x8000;
    const int baseOff = (ps - 32) * 1024 + q0 - 32;

    float4 acc[8];
#pragma unroll
    for (int kk = 0; kk < 8; ++kk) acc[kk] = make_float4(0.f, 0.f, 0.f, 0.f);

    const float* xim = x + ((size_t)(b * 3 + c) << 20);  // 1024*1024 plane

    float4 xv = make_float4(0.f, 0.f, 0.f, 0.f);
    int okc = 0;
    if (nact > 0) {
      const int co = s_colOff[0];
      okc = (qm >> ((co >> 6) & 15)) & (ym >> (co >> 16)) & 1;
      xv = *(const float4*)(xim + (okc ? (baseOff + co) : 0));
    }

    for (int it = 0; it < nact; ++it) {
      const int itn = (it + 1 < nact) ? it + 1 : it;
      const int con = s_colOff[itn];
      const int okn = (qm >> ((con >> 6) & 15)) & (ym >> (con >> 16)) & 1;
      const float4 xn = *(const float4*)(xim + (okn ? (baseOff + con) : 0));

      float4 xc = xv;
      xc.x = okc ? xc.x : 0.0f;
      xc.y = okc ? xc.y : 0.0f;
      xc.z = okc ? xc.z : 0.0f;
      xc.w = okc ? xc.w : 0.0f;

      const float4 wa = *(const float4*)&s_cw[it * 8 + 0];  // ds_read_b128
      const float4 wb = *(const float4*)&s_cw[it * 8 + 4];  // ds_read_b128

#define ACC_K(kk, wv_)                                            \
      { acc[kk].x += (wv_) * xc.x; acc[kk].y += (wv_) * xc.y;     \
        acc[kk].z += (wv_) * xc.z; acc[kk].w += (wv_) * xc.w; }
      ACC_K(0, wa.x) ACC_K(1, wa.y) ACC_K(2, wa.z) ACC_K(3, wa.w)
      ACC_K(4, wb.x) ACC_K(5, wb.y) ACC_K(6, wb.z) ACC_K(7, wb.w)
#undef ACC_K

      xv = xn;
      okc = okn;
    }

#pragma unroll
    for (int kk = 0; kk < 8; ++kk) {
      const size_t obase = ((size_t)((b * 16 + k0 + kk) * 3 + c)) << 14;
      float4* dst = (float4*)(out + obase + (size_t)ps * 128 + q0);
      __builtin_nontemporal_store(acc[kk].x, &dst->x);
      __builtin_nontemporal_store(acc[kk].y, &dst->y);
      __builtin_nontemporal_store(acc[kk].z, &dst->z);
      __builtin_nontemporal_store(acc[kk].w, &dst->w);
    }
  }
}

extern "C" void kernel_launch(void* const* d_in, const int* in_sizes, int n_in,
                              void* d_out, int out_size, void* d_ws, size_t ws_size,
                              hipStream_t stream) {
  const float* x_high = (const float*)d_in[0];
  const float* scores = (const float*)d_in[1];
  float* out = (float*)d_out;
  uint32_t* counts = (uint32_t*)d_ws;          // 8*16*256 u32 = 128 KB
  uint32_t* bar = counts + 8 * 16 * DDIM;      // barrier counter at +128 KB

  hipMemsetAsync(counts, 0, (8 * 16 * DDIM + 16) * sizeof(uint32_t), stream);
  fused_kernel<<<GRID, 256, 0, stream>>>(x_high, scores, counts, bar, out);
}

// Round 3
// 172.196 us; speedup vs baseline: 1.7741x; 1.7741x over previous
//
#include <hip/hip_runtime.h>
#include <stdint.h>

// DPS_55336358642719  (round-9: back to 2 dispatches, no grid barrier)
// in[0]: x_high  (8,3,1024,1024) f32
// in[1]: scores  (8,16,16)       f32
// out:   patches (128,3,128,128) f32
//
// ws layout: sel[8][500][16] u8 (64000 B) — sel[b][n][r] = selected index d
//   (write-once per iteration, every byte covered -> no zeroing, no atomics,
//    poison-safe; replaces counts[] + its hipMemsetAsync dispatch)
//
// NOTE: measured harness floor is ~145 us of fillBufferAligned re-poison
// (402 MB @ ~82% HBM peak) per timed iteration — not addressable from here.
// Round-8 post-mortem: fused persistent kernel + agent-scope barrier spin
// stalled 177 us in coherence traffic (VALUBusy 8.9%) — grid barriers on
// CDNA4 invalidate per-XCD L2 per acquire; do NOT fuse via spin barrier.
// Steady-state evidence: x is L3-resident (FETCH~0), patches is not
// HBM-fetch-bound.

#define NSAMP 500
#define DDIM  256

// ---------------- threefry2x32 (JAX-exact, key = seed 42) ----------------
__device__ __forceinline__ void threefry2x32_0_42(uint32_t x0, uint32_t x1,
                                                  uint32_t& o0, uint32_t& o1) {
  const uint32_t k0 = 0u, k1 = 42u;
  const uint32_t k2 = k0 ^ k1 ^ 0x1BD11BDAu;
  x0 += k0; x1 += k1;
#define TF_ROUND(r) { x0 += x1; x1 = (x1 << (r)) | (x1 >> (32 - (r))); x1 ^= x0; }
  TF_ROUND(13) TF_ROUND(15) TF_ROUND(26) TF_ROUND(6)
  x0 += k1; x1 += k2 + 1u;
  TF_ROUND(17) TF_ROUND(29) TF_ROUND(16) TF_ROUND(24)
  x0 += k2; x1 += k0 + 2u;
  TF_ROUND(13) TF_ROUND(15) TF_ROUND(26) TF_ROUND(6)
  x0 += k0; x1 += k1 + 3u;
  TF_ROUND(17) TF_ROUND(29) TF_ROUND(16) TF_ROUND(24)
  x0 += k1; x1 += k2 + 4u;
  TF_ROUND(13) TF_ROUND(15) TF_ROUND(26) TF_ROUND(6)
  x0 += k2; x1 += k0 + 5u;
#undef TF_ROUND
  o0 = x0; o1 = x1;
}

// XLA's ErfInv32 (Giles polynomial), fp-contract off for fidelity
__device__ __forceinline__ float xla_erfinv(float x) {
#pragma clang fp contract(off)
  float w = -log1pf(-x * x);
  float p;
  if (w < 5.0f) {
    w = w - 2.5f;
    p = 2.81022636e-08f;
    p = 3.43273939e-07f + p * w;
    p = -3.5233877e-06f + p * w;
    p = -4.39150654e-06f + p * w;
    p = 0.00021858087f + p * w;
    p = -0.00125372503f + p * w;
    p = -0.00417768164f + p * w;
    p = 0.246640727f + p * w;
    p = 1.50140941f + p * w;
  } else {
    w = sqrtf(w) - 3.0f;
    p = -0.000200214257f;
    p = 0.000100950558f + p * w;
    p = 0.00134934322f + p * w;
    p = -0.00367342844f + p * w;
    p = 0.00573950773f + p * w;
    p = -0.0076224613f + p * w;
    p = 0.00943887047f + p * w;
    p = 1.00167406f + p * w;
    p = 2.83297682f + p * w;
  }
  return p * x;
}

// One block = one b, 4 consecutive samples. Thread d owns index d.
// Per-(b,d) normalization hoisted out of the sample loop (sample-invariant).
// Screened exact selection (verified r7/r8): T_lb = min of 16 group-of-16
// maxes => 16th largest >= T_lb; ranks among candidates == full ranks.
__global__ void __launch_bounds__(256) topk_kernel(const float* __restrict__ scores,
                                                   uint8_t* __restrict__ sel) {
#pragma clang fp contract(off)
  const int g = blockIdx.x;           // b*125 + group
  const int b = g / 125;
  const int n0 = (g - b * 125) << 2;  // 4 samples per block
  const int d = threadIdx.x;
  const int lane = d & 63, wv = d >> 6;

  __shared__ float s_wmx[4], s_wmn[4], s_wtl[4];
  __shared__ int   s_wcc[4], s_wtot[4];
  __shared__ __align__(16) float s_candPv[DDIM];
  __shared__ int   s_candIdx[DDIM];
  __shared__ unsigned char s_selMark[DDIM];

  const float sc = scores[b * DDIM + d];

  // block min/max of scores: wave shuffles + tiny LDS combine (exact ops)
  float mx = sc, mn = sc;
  for (int off = 32; off > 0; off >>= 1) {
    mx = fmaxf(mx, __shfl_xor(mx, off));
    mn = fminf(mn, __shfl_xor(mn, off));
  }
  if (lane == 0) { s_wmx[wv] = mx; s_wmn[wv] = mn; }
  __syncthreads();
  mx = fmaxf(fmaxf(s_wmx[0], s_wmx[1]), fmaxf(s_wmx[2], s_wmx[3]));
  mn = fminf(fminf(s_wmn[0], s_wmn[1]), fminf(s_wmn[2], s_wmn[3]));
  const float denom = (mx - mn) + 1e-5f;
  const float sv = (sc - mn) / denom;   // sample-invariant (bit-identical order)

  for (int s = 0; s < 4; ++s) {
    const int n = n0 + s;
    s_selMark[d] = 0;

    // perturbed value (bit-identical expression order)
    const uint32_t j = (uint32_t)(b * (NSAMP * DDIM) + n * DDIM + d);
    uint32_t o0, o1;
    threefry2x32_0_42(0u, j, o0, o1);
    const uint32_t bits = o0 ^ o1;
    const float flo = -0.99999994f;  // nextafter(-1,0) in f32
    float f = __uint_as_float((bits >> 9) | 0x3f800000u) - 1.0f;
    float u = f * 2.0f + flo;
    u = fmaxf(flo, u);
    const float z = 1.41421356237f * xla_erfinv(u);
    const float pv = sv + z * 0.05f;

    // screen: T_lb = min over 16 groups-of-16 of group max
    float gmx = pv;
    gmx = fmaxf(gmx, __shfl_xor(gmx, 1));
    gmx = fmaxf(gmx, __shfl_xor(gmx, 2));
    gmx = fmaxf(gmx, __shfl_xor(gmx, 4));
    gmx = fmaxf(gmx, __shfl_xor(gmx, 8));
    float tl = gmx;
    tl = fminf(tl, __shfl_xor(tl, 16));
    tl = fminf(tl, __shfl_xor(tl, 32));
    if (lane == 0) s_wtl[wv] = tl;
    __syncthreads();
    const float T_lb = fminf(fminf(s_wtl[0], s_wtl[1]), fminf(s_wtl[2], s_wtl[3]));

    // compact candidates ascending by d (preserves index order)
    const bool candf = (pv >= T_lb);
    const unsigned long long cm = __ballot(candf);
    if (lane == 0) s_wcc[wv] = __popcll(cm);
    __syncthreads();
    int cbase = 0;
    for (int w2 = 0; w2 < wv; ++w2) cbase += s_wcc[w2];
    const int C = s_wcc[0] + s_wcc[1] + s_wcc[2] + s_wcc[3];  // >= 16
    if (candf) {
      const int pos = cbase + __popcll(cm & ((1ull << lane) - 1ull));
      s_candPv[pos] = pv;
      s_candIdx[pos] = d;
    }
    const int Cr = (C + 3) & ~3;
    if (d >= C && d < Cr) s_candPv[d] = -1e30f;
    __syncthreads();

    // exact rank among candidates (any value > or == a candidate is itself
    // >= T_lb, hence also a candidate; compaction preserves index order)
    if (d < C) {
      const float cpv = s_candPv[d];
      int gc = 0, eqb = 0;
      const float4* c4 = (const float4*)s_candPv;
      for (int e4 = 0; e4 < (Cr >> 2); ++e4) {
        const float4 o = c4[e4];
        const int e = e4 << 2;
        gc += (o.x > cpv); gc += (o.y > cpv); gc += (o.z > cpv); gc += (o.w > cpv);
        eqb += (o.x == cpv) & ((e + 0) < d);
        eqb += (o.y == cpv) & ((e + 1) < d);
        eqb += (o.z == cpv) & ((e + 2) < d);
        eqb += (o.w == cpv) & ((e + 3) < d);
      }
      if ((gc + eqb) < 16) s_selMark[s_candIdx[d]] = 1;
    }
    __syncthreads();

    // rank among selected, ascending index (the jnp.sort step); ranks 0..15
    // are a bijection -> write-once byte per rank, no atomics needed.
    const bool selb = s_selMark[d] != 0;
    const unsigned long long m = __ballot(selb);
    if (lane == 0) s_wtot[wv] = __popcll(m);
    __syncthreads();
    int r = __popcll(m & ((1ull << lane) - 1ull));
    for (int w2 = 0; w2 < wv; ++w2) r += s_wtot[w2];

    if (selb) sel[(((size_t)(b * NSAMP + n)) << 4) + r] = (uint8_t)d;
    __syncthreads();   // guard LDS reuse for next sample
  }
}

// grid: (16 p-tiles, 3 c, 8 b * 2 kgroups); block 256 = 32 q-groups x 8 rows.
// Weights rebuilt from sel[] via an 8x256 LDS histogram (2 coalesced u64
// loads + 16 LDS atomics per thread), then the verified compact+FMA loop.
__global__ void __launch_bounds__(256) patches_kernel(const float* __restrict__ x,
                                                      const uint8_t* __restrict__ sel,
                                                      float* __restrict__ out) {
  const int p0 = blockIdx.x << 3;     // 8 rows per block
  const int c  = blockIdx.y;
  const int zb = blockIdx.z;          // b*2 + kg
  const int b  = zb >> 1;
  const int k0 = (zb & 1) << 3;       // 0 or 8

  __shared__ uint32_t s_hist[8 * DDIM];         // [kk][d] counts (8 KB)
  __shared__ __align__(16) float s_cw[DDIM * 8];  // compacted [pos][k]
  __shared__ int s_colOff[DDIM];                // compacted i*65536 + w*64
  __shared__ int s_wcnt[4];

  const int tid = threadIdx.x;
  const int lane = tid & 63, wvi = tid >> 6;

  // ---- histogram from sel bytes ----
#pragma unroll
  for (int kk = 0; kk < 8; ++kk) s_hist[(kk << 8) + tid] = 0;
  __syncthreads();
  for (int s2 = tid; s2 < NSAMP; s2 += 256) {
    const uint64_t v8 =
        *(const uint64_t*)(sel + (((size_t)(b * NSAMP + s2)) << 4) + k0);
#pragma unroll
    for (int kk = 0; kk < 8; ++kk) {
      const int dd = (int)((v8 >> (kk * 8)) & 255u);
      atomicAdd(&s_hist[(kk << 8) + dd], 1u);
    }
  }
  __syncthreads();

  // load weights (from LDS hist), compact active columns ascending
  {
    float wreg[8];
    bool any = false;
#pragma unroll
    for (int kk = 0; kk < 8; ++kk) {
      float w = (float)s_hist[(kk << 8) + tid] / 500.0f;
      wreg[kk] = w;
      any = any || (w != 0.0f);
    }
    unsigned long long m = __ballot(any);
    if (lane == 0) s_wcnt[wvi] = __popcll(m);
    __syncthreads();
    int base = 0;
    for (int w2 = 0; w2 < wvi; ++w2) base += s_wcnt[w2];
    if (any) {
      int pos = base + __popcll(m & ((1ull << lane) - 1ull));
      s_colOff[pos] = ((tid >> 4) << 16) | ((tid & 15) << 6);  // i*65536 + w*64
#pragma unroll
      for (int kk = 0; kk < 8; ++kk) s_cw[pos * 8 + kk] = wreg[kk];
    }
    __syncthreads();
  }
  const int nact = s_wcnt[0] + s_wcnt[1] + s_wcnt[2] + s_wcnt[3];

  const int q0   = (tid & 31) << 2;   // 0,4,...,124
  const int slot = tid >> 5;          // 0..7
  const int ps   = p0 + slot;

  // bounds masks: bit w of qm / bit i of ym says the float4 is in-bounds
  int qm = 0xFFFF, ym = 0xFFFF;
  if (q0 < 32) qm &= ~1;
  if (q0 > 92) qm &= ~0x8000;
  if (ps < 32) ym &= ~1;
  if (ps > 95) ym &= ~0x8000;
  const int baseOff = (ps - 32) * 1024 + q0 - 32;  // add colOff -> x offset

  float4 acc[8];
#pragma unroll
  for (int kk = 0; kk < 8; ++kk) acc[kk] = make_float4(0.f, 0.f, 0.f, 0.f);

  const float* xim = x + ((size_t)(b * 3 + c) << 20);  // 1024*1024 plane

  float4 xv = make_float4(0.f, 0.f, 0.f, 0.f);
  int okc = 0;
  if (nact > 0) {
    const int co = s_colOff[0];
    okc = (qm >> ((co >> 6) & 15)) & (ym >> (co >> 16)) & 1;
    xv = *(const float4*)(xim + (okc ? (baseOff + co) : 0));
  }

  for (int it = 0; it < nact; ++it) {
    // issue next x load before this iteration's FMAs (1-deep prefetch)
    const int itn = (it + 1 < nact) ? it + 1 : it;
    const int con = s_colOff[itn];
    const int okn = (qm >> ((con >> 6) & 15)) & (ym >> (con >> 16)) & 1;
    const float4 xn = *(const float4*)(xim + (okn ? (baseOff + con) : 0));

    float4 xc = xv;
    xc.x = okc ? xc.x : 0.0f;
    xc.y = okc ? xc.y : 0.0f;
    xc.z = okc ? xc.z : 0.0f;
    xc.w = okc ? xc.w : 0.0f;

    const float4 wa = *(const float4*)&s_cw[it * 8 + 0];  // ds_read_b128
    const float4 wb = *(const float4*)&s_cw[it * 8 + 4];  // ds_read_b128

#define ACC_K(kk, wv_)                                            \
    { acc[kk].x += (wv_) * xc.x; acc[kk].y += (wv_) * xc.y;       \
      acc[kk].z += (wv_) * xc.z; acc[kk].w += (wv_) * xc.w; }
    ACC_K(0, wa.x) ACC_K(1, wa.y) ACC_K(2, wa.z) ACC_K(3, wa.w)
    ACC_K(4, wb.x) ACC_K(5, wb.y) ACC_K(6, wb.z) ACC_K(7, wb.w)
#undef ACC_K

    xv = xn;
    okc = okn;
  }

#pragma unroll
  for (int kk = 0; kk < 8; ++kk) {
    const size_t obase = ((size_t)((b * 16 + k0 + kk) * 3 + c)) << 14;  // 128*128
    float4* dst = (float4*)(out + obase + (size_t)ps * 128 + q0);
    __builtin_nontemporal_store(acc[kk].x, &dst->x);
    __builtin_nontemporal_store(acc[kk].y, &dst->y);
    __builtin_nontemporal_store(acc[kk].z, &dst->z);
    __builtin_nontemporal_store(acc[kk].w, &dst->w);
  }
}

extern "C" void kernel_launch(void* const* d_in, const int* in_sizes, int n_in,
                              void* d_out, int out_size, void* d_ws, size_t ws_size,
                              hipStream_t stream) {
  const float* x_high = (const float*)d_in[0];
  const float* scores = (const float*)d_in[1];
  float* out = (float*)d_out;
  uint8_t* sel = (uint8_t*)d_ws;  // 8*500*16 bytes, fully overwritten each run

  topk_kernel<<<8 * 125, 256, 0, stream>>>(scores, sel);
  patches_kernel<<<dim3(16, 3, 16), 256, 0, stream>>>(x_high, sel, out);
}

// Round 5
// 170.018 us; speedup vs baseline: 1.7968x; 1.0128x over previous
//
#include <hip/hip_runtime.h>
#include <stdint.h>

// DPS_55336358642719  (round-11: verbatim revert to verified round-9)
// in[0]: x_high  (8,3,1024,1024) f32
// in[1]: scores  (8,16,16)       f32
// out:   patches (128,3,128,128) f32
//
// ws layout: sel[8][500][16] u8 (64000 B) — sel[b][n][r] = selected index d
//   (write-once per iteration, every byte covered -> no zeroing, no atomics,
//    poison-safe; replaces counts[] + its hipMemsetAsync dispatch)
//
// NOTE: measured harness floor is ~145 us of fillBufferAligned re-poison
// (402 MB @ ~82% HBM peak) per timed iteration — not addressable from here.
// Round-8 lesson: do NOT fuse via agent-scope spin barrier (coherence stall,
// 194 us kernel @ 8.9% VALUBusy). Round-10 lesson: end-of-kernel x-prefetch
// keep-alive in topk was perf-neutral AND tripped post-timing divergence —
// reverted; do not re-add.
// Remaining accounting: fills ~145 + patches ~18.3 (mandatory HBM fetch of
// ~90MB x active-union + 25MB writes) + topk ~5 (VALU) + gaps ~2 ≈ 170 us.

#define NSAMP 500
#define DDIM  256

// ---------------- threefry2x32 (JAX-exact, key = seed 42) ----------------
__device__ __forceinline__ void threefry2x32_0_42(uint32_t x0, uint32_t x1,
                                                  uint32_t& o0, uint32_t& o1) {
  const uint32_t k0 = 0u, k1 = 42u;
  const uint32_t k2 = k0 ^ k1 ^ 0x1BD11BDAu;
  x0 += k0; x1 += k1;
#define TF_ROUND(r) { x0 += x1; x1 = (x1 << (r)) | (x1 >> (32 - (r))); x1 ^= x0; }
  TF_ROUND(13) TF_ROUND(15) TF_ROUND(26) TF_ROUND(6)
  x0 += k1; x1 += k2 + 1u;
  TF_ROUND(17) TF_ROUND(29) TF_ROUND(16) TF_ROUND(24)
  x0 += k2; x1 += k0 + 2u;
  TF_ROUND(13) TF_ROUND(15) TF_ROUND(26) TF_ROUND(6)
  x0 += k0; x1 += k1 + 3u;
  TF_ROUND(17) TF_ROUND(29) TF_ROUND(16) TF_ROUND(24)
  x0 += k1; x1 += k2 + 4u;
  TF_ROUND(13) TF_ROUND(15) TF_ROUND(26) TF_ROUND(6)
  x0 += k2; x1 += k0 + 5u;
#undef TF_ROUND
  o0 = x0; o1 = x1;
}

// XLA's ErfInv32 (Giles polynomial), fp-contract off for fidelity
__device__ __forceinline__ float xla_erfinv(float x) {
#pragma clang fp contract(off)
  float w = -log1pf(-x * x);
  float p;
  if (w < 5.0f) {
    w = w - 2.5f;
    p = 2.81022636e-08f;
    p = 3.43273939e-07f + p * w;
    p = -3.5233877e-06f + p * w;
    p = -4.39150654e-06f + p * w;
    p = 0.00021858087f + p * w;
    p = -0.00125372503f + p * w;
    p = -0.00417768164f + p * w;
    p = 0.246640727f + p * w;
    p = 1.50140941f + p * w;
  } else {
    w = sqrtf(w) - 3.0f;
    p = -0.000200214257f;
    p = 0.000100950558f + p * w;
    p = 0.00134934322f + p * w;
    p = -0.00367342844f + p * w;
    p = 0.00573950773f + p * w;
    p = -0.0076224613f + p * w;
    p = 0.00943887047f + p * w;
    p = 1.00167406f + p * w;
    p = 2.83297682f + p * w;
  }
  return p * x;
}

// One block = one b, 4 consecutive samples. Thread d owns index d.
// Per-(b,d) normalization hoisted out of the sample loop (sample-invariant).
// Screened exact selection (verified r7/r8): T_lb = min of 16 group-of-16
// maxes => 16th largest >= T_lb; ranks among candidates == full ranks.
__global__ void __launch_bounds__(256) topk_kernel(const float* __restrict__ scores,
                                                   uint8_t* __restrict__ sel) {
#pragma clang fp contract(off)
  const int g = blockIdx.x;           // b*125 + group
  const int b = g / 125;
  const int n0 = (g - b * 125) << 2;  // 4 samples per block
  const int d = threadIdx.x;
  const int lane = d & 63, wv = d >> 6;

  __shared__ float s_wmx[4], s_wmn[4], s_wtl[4];
  __shared__ int   s_wcc[4], s_wtot[4];
  __shared__ __align__(16) float s_candPv[DDIM];
  __shared__ int   s_candIdx[DDIM];
  __shared__ unsigned char s_selMark[DDIM];

  const float sc = scores[b * DDIM + d];

  // block min/max of scores: wave shuffles + tiny LDS combine (exact ops)
  float mx = sc, mn = sc;
  for (int off = 32; off > 0; off >>= 1) {
    mx = fmaxf(mx, __shfl_xor(mx, off));
    mn = fminf(mn, __shfl_xor(mn, off));
  }
  if (lane == 0) { s_wmx[wv] = mx; s_wmn[wv] = mn; }
  __syncthreads();
  mx = fmaxf(fmaxf(s_wmx[0], s_wmx[1]), fmaxf(s_wmx[2], s_wmx[3]));
  mn = fminf(fminf(s_wmn[0], s_wmn[1]), fminf(s_wmn[2], s_wmn[3]));
  const float denom = (mx - mn) + 1e-5f;
  const float sv = (sc - mn) / denom;   // sample-invariant (bit-identical order)

  for (int s = 0; s < 4; ++s) {
    const int n = n0 + s;
    s_selMark[d] = 0;

    // perturbed value (bit-identical expression order)
    const uint32_t j = (uint32_t)(b * (NSAMP * DDIM) + n * DDIM + d);
    uint32_t o0, o1;
    threefry2x32_0_42(0u, j, o0, o1);
    const uint32_t bits = o0 ^ o1;
    const float flo = -0.99999994f;  // nextafter(-1,0) in f32
    float f = __uint_as_float((bits >> 9) | 0x3f800000u) - 1.0f;
    float u = f * 2.0f + flo;
    u = fmaxf(flo, u);
    const float z = 1.41421356237f * xla_erfinv(u);
    const float pv = sv + z * 0.05f;

    // screen: T_lb = min over 16 groups-of-16 of group max
    float gmx = pv;
    gmx = fmaxf(gmx, __shfl_xor(gmx, 1));
    gmx = fmaxf(gmx, __shfl_xor(gmx, 2));
    gmx = fmaxf(gmx, __shfl_xor(gmx, 4));
    gmx = fmaxf(gmx, __shfl_xor(gmx, 8));
    float tl = gmx;
    tl = fminf(tl, __shfl_xor(tl, 16));
    tl = fminf(tl, __shfl_xor(tl, 32));
    if (lane == 0) s_wtl[wv] = tl;
    __syncthreads();
    const float T_lb = fminf(fminf(s_wtl[0], s_wtl[1]), fminf(s_wtl[2], s_wtl[3]));

    // compact candidates ascending by d (preserves index order)
    const bool candf = (pv >= T_lb);
    const unsigned long long cm = __ballot(candf);
    if (lane == 0) s_wcc[wv] = __popcll(cm);
    __syncthreads();
    int cbase = 0;
    for (int w2 = 0; w2 < wv; ++w2) cbase += s_wcc[w2];
    const int C = s_wcc[0] + s_wcc[1] + s_wcc[2] + s_wcc[3];  // >= 16
    if (candf) {
      const int pos = cbase + __popcll(cm & ((1ull << lane) - 1ull));
      s_candPv[pos] = pv;
      s_candIdx[pos] = d;
    }
    const int Cr = (C + 3) & ~3;
    if (d >= C && d < Cr) s_candPv[d] = -1e30f;
    __syncthreads();

    // exact rank among candidates (any value > or == a candidate is itself
    // >= T_lb, hence also a candidate; compaction preserves index order)
    if (d < C) {
      const float cpv = s_candPv[d];
      int gc = 0, eqb = 0;
      const float4* c4 = (const float4*)s_candPv;
      for (int e4 = 0; e4 < (Cr >> 2); ++e4) {
        const float4 o = c4[e4];
        const int e = e4 << 2;
        gc += (o.x > cpv); gc += (o.y > cpv); gc += (o.z > cpv); gc += (o.w > cpv);
        eqb += (o.x == cpv) & ((e + 0) < d);
        eqb += (o.y == cpv) & ((e + 1) < d);
        eqb += (o.z == cpv) & ((e + 2) < d);
        eqb += (o.w == cpv) & ((e + 3) < d);
      }
      if ((gc + eqb) < 16) s_selMark[s_candIdx[d]] = 1;
    }
    __syncthreads();

    // rank among selected, ascending index (the jnp.sort step); ranks 0..15
    // are a bijection -> write-once byte per rank, no atomics needed.
    const bool selb = s_selMark[d] != 0;
    const unsigned long long m = __ballot(selb);
    if (lane == 0) s_wtot[wv] = __popcll(m);
    __syncthreads();
    int r = __popcll(m & ((1ull << lane) - 1ull));
    for (int w2 = 0; w2 < wv; ++w2) r += s_wtot[w2];

    if (selb) sel[(((size_t)(b * NSAMP + n)) << 4) + r] = (uint8_t)d;
    __syncthreads();   // guard LDS reuse for next sample
  }
}

// grid: (16 p-tiles, 3 c, 8 b * 2 kgroups); block 256 = 32 q-groups x 8 rows.
// Weights rebuilt from sel[] via an 8x256 LDS histogram (2 coalesced u64
// loads + 16 LDS atomics per thread), then the verified compact+FMA loop.
__global__ void __launch_bounds__(256) patches_kernel(const float* __restrict__ x,
                                                      const uint8_t* __restrict__ sel,
                                                      float* __restrict__ out) {
  const int p0 = blockIdx.x << 3;     // 8 rows per block
  const int c  = blockIdx.y;
  const int zb = blockIdx.z;          // b*2 + kg
  const int b  = zb >> 1;
  const int k0 = (zb & 1) << 3;       // 0 or 8

  __shared__ uint32_t s_hist[8 * DDIM];         // [kk][d] counts (8 KB)
  __shared__ __align__(16) float s_cw[DDIM * 8];  // compacted [pos][k]
  __shared__ int s_colOff[DDIM];                // compacted i*65536 + w*64
  __shared__ int s_wcnt[4];

  const int tid = threadIdx.x;
  const int lane = tid & 63, wvi = tid >> 6;

  // ---- histogram from sel bytes ----
#pragma unroll
  for (int kk = 0; kk < 8; ++kk) s_hist[(kk << 8) + tid] = 0;
  __syncthreads();
  for (int s2 = tid; s2 < NSAMP; s2 += 256) {
    const uint64_t v8 =
        *(const uint64_t*)(sel + (((size_t)(b * NSAMP + s2)) << 4) + k0);
#pragma unroll
    for (int kk = 0; kk < 8; ++kk) {
      const int dd = (int)((v8 >> (kk * 8)) & 255u);
      atomicAdd(&s_hist[(kk << 8) + dd], 1u);
    }
  }
  __syncthreads();

  // load weights (from LDS hist), compact active columns ascending
  {
    float wreg[8];
    bool any = false;
#pragma unroll
    for (int kk = 0; kk < 8; ++kk) {
      float w = (float)s_hist[(kk << 8) + tid] / 500.0f;
      wreg[kk] = w;
      any = any || (w != 0.0f);
    }
    unsigned long long m = __ballot(any);
    if (lane == 0) s_wcnt[wvi] = __popcll(m);
    __syncthreads();
    int base = 0;
    for (int w2 = 0; w2 < wvi; ++w2) base += s_wcnt[w2];
    if (any) {
      int pos = base + __popcll(m & ((1ull << lane) - 1ull));
      s_colOff[pos] = ((tid >> 4) << 16) | ((tid & 15) << 6);  // i*65536 + w*64
#pragma unroll
      for (int kk = 0; kk < 8; ++kk) s_cw[pos * 8 + kk] = wreg[kk];
    }
    __syncthreads();
  }
  const int nact = s_wcnt[0] + s_wcnt[1] + s_wcnt[2] + s_wcnt[3];

  const int q0   = (tid & 31) << 2;   // 0,4,...,124
  const int slot = tid >> 5;          // 0..7
  const int ps   = p0 + slot;

  // bounds masks: bit w of qm / bit i of ym says the float4 is in-bounds
  int qm = 0xFFFF, ym = 0xFFFF;
  if (q0 < 32) qm &= ~1;
  if (q0 > 92) qm &= ~0x8000;
  if (ps < 32) ym &= ~1;
  if (ps > 95) ym &= ~0x8000;
  const int baseOff = (ps - 32) * 1024 + q0 - 32;  // add colOff -> x offset

  float4 acc[8];
#pragma unroll
  for (int kk = 0; kk < 8; ++kk) acc[kk] = make_float4(0.f, 0.f, 0.f, 0.f);

  const float* xim = x + ((size_t)(b * 3 + c) << 20);  // 1024*1024 plane

  float4 xv = make_float4(0.f, 0.f, 0.f, 0.f);
  int okc = 0;
  if (nact > 0) {
    const int co = s_colOff[0];
    okc = (qm >> ((co >> 6) & 15)) & (ym >> (co >> 16)) & 1;
    xv = *(const float4*)(xim + (okc ? (baseOff + co) : 0));
  }

  for (int it = 0; it < nact; ++it) {
    // issue next x load before this iteration's FMAs (1-deep prefetch)
    const int itn = (it + 1 < nact) ? it + 1 : it;
    const int con = s_colOff[itn];
    const int okn = (qm >> ((con >> 6) & 15)) & (ym >> (con >> 16)) & 1;
    const float4 xn = *(const float4*)(xim + (okn ? (baseOff + con) : 0));

    float4 xc = xv;
    xc.x = okc ? xc.x : 0.0f;
    xc.y = okc ? xc.y : 0.0f;
    xc.z = okc ? xc.z : 0.0f;
    xc.w = okc ? xc.w : 0.0f;

    const float4 wa = *(const float4*)&s_cw[it * 8 + 0];  // ds_read_b128
    const float4 wb = *(const float4*)&s_cw[it * 8 + 4];  // ds_read_b128

#define ACC_K(kk, wv_)                                            \
    { acc[kk].x += (wv_) * xc.x; acc[kk].y += (wv_) * xc.y;       \
      acc[kk].z += (wv_) * xc.z; acc[kk].w += (wv_) * xc.w; }
    ACC_K(0, wa.x) ACC_K(1, wa.y) ACC_K(2, wa.z) ACC_K(3, wa.w)
    ACC_K(4, wb.x) ACC_K(5, wb.y) ACC_K(6, wb.z) ACC_K(7, wb.w)
#undef ACC_K

    xv = xn;
    okc = okn;
  }

#pragma unroll
  for (int kk = 0; kk < 8; ++kk) {
    const size_t obase = ((size_t)((b * 16 + k0 + kk) * 3 + c)) << 14;  // 128*128
    float4* dst = (float4*)(out + obase + (size_t)ps * 128 + q0);
    __builtin_nontemporal_store(acc[kk].x, &dst->x);
    __builtin_nontemporal_store(acc[kk].y, &dst->y);
    __builtin_nontemporal_store(acc[kk].z, &dst->z);
    __builtin_nontemporal_store(acc[kk].w, &dst->w);
  }
}

extern "C" void kernel_launch(void* const* d_in, const int* in_sizes, int n_in,
                              void* d_out, int out_size, void* d_ws, size_t ws_size,
                              hipStream_t stream) {
  const float* x_high = (const float*)d_in[0];
  const float* scores = (const float*)d_in[1];
  float* out = (float*)d_out;
  uint8_t* sel = (uint8_t*)d_ws;  // 8*500*16 bytes, fully overwritten each run

  topk_kernel<<<8 * 125, 256, 0, stream>>>(scores, sel);
  patches_kernel<<<dim3(16, 3, 16), 256, 0, stream>>>(x_high, sel, out);
}